// Round 6
// baseline (837.088 us; speedup 1.0000x reference)
//
#include <hip/hip_runtime.h>

#define NN 12288
#define FF 128
#define HH 64
#define CC 16
#define CAP 128

#define NBLD 2048                  // scan blocks (8/CU, no LDS -> 32 waves/CU)
#define NTHR (NBLD * 256)          // 524288 threads
#define NV4  (NN * (NN / 4))       // 37,748,736 vec4 in adj
#define NIT  (NV4 / NTHR)          // 72 iterations exactly (no remainder)

typedef float f32x4 __attribute__((ext_vector_type(4)));
typedef unsigned long long u64;

// ---------------------------------------------------------------------------
// Pass 1 (k_scan), v3: ZERO-CROSS-LANE streaming scan -> byte-mask.
// R0-R5 builds all ran at ~1.7 TB/s effective regardless of structure; the
// one remaining common element was __ballot (4 per vec4) consuming each load.
// This version has NO ballot / shfl / atomic / LDS / data-dependent branch:
// each lane computes a 4-bit nibble mask of ITS OWN vec4 in pure VALU and
// stores one byte; a wave stores 64 contiguous bytes (1 cacheline txn).
// Body = load 16B -> ~8 VALU -> store 1B, 3-deep prefetch, global-sequential
// sweep. This is maximally fill-kernel-shaped while reading all of adj.
// Encoding: bmp8[vi] bit q <=> adj[vi*4+q] != 0.
// ---------------------------------------------------------------------------
__global__ __launch_bounds__(256) void k_scan(const float* __restrict__ adj,
                                              unsigned char* __restrict__ bmp8) {
    const f32x4* av = (const f32x4*)adj;
    unsigned vi = blockIdx.x * 256 + threadIdx.x;   // vec4 index, stride NTHR
    f32x4 c0 = av[vi];
    f32x4 c1 = av[vi + NTHR];
    f32x4 c2 = av[vi + 2u * NTHR];
    for (int t = 0; t < NIT; ++t) {
        f32x4 c3 = {};
        if (t + 3 < NIT) c3 = av[vi + 3u * NTHR];   // uniform branch
        const int m = (c0[0] != 0.f ? 1 : 0) | (c0[1] != 0.f ? 2 : 0)
                    | (c0[2] != 0.f ? 4 : 0) | (c0[3] != 0.f ? 8 : 0);
        bmp8[vi] = (unsigned char)m;                // 64B/wave, coalesced
        c0 = c1; c1 = c2; c2 = c3;
        vi += NTHR;
    }
}

// ---------------------------------------------------------------------------
// Pass 2 (k_compact): compaction over the 37.75 MB L2/LLC-resident byte-mask.
// Wave per row: 3072 bytes = 384 u64 words, 6 coalesced u64 loads/lane;
// popcount + wave prefix-scan gives deterministic slot bases (no atomics);
// each lane serially expands its ~0.4 expected set bits.
// Bit b of word (j*64+lane): vec4 = (j*64+lane)*8 + (b>>3), comp = b&7 (<=3).
// ---------------------------------------------------------------------------
__global__ __launch_bounds__(256) void k_compact(const u64* __restrict__ bmp,
                                                 int* __restrict__ cnt,
                                                 int* __restrict__ nbr) {
    const int wave = threadIdx.x >> 6;
    const int lane = threadIdx.x & 63;
    const int row  = blockIdx.x * 4 + wave;

    const u64* rw = bmp + (size_t)row * 384;   // 3072 bytes / 8
    u64 w[6];
    int c = 0;
    #pragma unroll
    for (int j = 0; j < 6; ++j) {
        w[j] = rw[j * 64 + lane];              // 512B/instr, coalesced
        c += __popcll(w[j]);
    }

    int incl = c;                               // wave inclusive prefix scan
    #pragma unroll
    for (int d = 1; d < 64; d <<= 1) {
        const int n = __shfl_up(incl, d);
        if (lane >= d) incl += n;
    }
    const int total = __shfl(incl, 63);
    int base = incl - c;                        // exclusive base for this lane

    int* my = nbr + (size_t)row * CAP;
    #pragma unroll
    for (int j = 0; j < 6; ++j) {
        u64 x = w[j];
        const int v8 = (j * 64 + lane) * 8;     // first vec4 of this word
        while (x) {
            const int b = __ffsll((long long)x) - 1;
            if (base < CAP) my[base] = ((v8 + (b >> 3)) << 2) + (b & 7);
            ++base;
            x &= x - 1;
        }
    }
    if (lane == 0) cnt[row] = total;            // true degree (uncapped)
}

// ---------------------------------------------------------------------------
// k_proj: xp[i,:] = dinv_i * (x_i @ W1)   [64]   ((Ax)W1 == A(xW1))
// ---------------------------------------------------------------------------
__global__ __launch_bounds__(512) void k_proj(const float* __restrict__ W1,
                                              const int* __restrict__ cnt,
                                              const float* __restrict__ x,
                                              float* __restrict__ xp) {
    __shared__ float s_W1[FF * HH];   // 32 KB
    __shared__ float s_x[8][FF];      // 4 KB
    {
        const f32x4* Wv = (const f32x4*)W1;
        f32x4* Sv = (f32x4*)s_W1;
        for (int t = threadIdx.x; t < FF * HH / 4; t += 512) Sv[t] = Wv[t];
    }
    const int wave = threadIdx.x >> 6;
    const int lane = threadIdx.x & 63;
    const int i = blockIdx.x * 8 + wave;

    const float2 xv = *(const float2*)(x + (size_t)i * FF + 2 * lane);
    s_x[wave][2 * lane]     = xv.x;
    s_x[wave][2 * lane + 1] = xv.y;
    __syncthreads();
    float h = 0.f;
    #pragma unroll 8
    for (int f = 0; f < FF; ++f) h += s_x[wave][f] * s_W1[f * HH + lane];
    const float di = 1.0f / sqrtf((float)(cnt[i] + 1));   // +1 = self loop
    xp[(size_t)i * HH + lane] = di * h;
}

// ---------------------------------------------------------------------------
// k_agg1: h1s[i,:] = dinv_i * relu(dinv_i * (xp_i + sum_nbr xp_j))
// (trailing dinv_i pre-folds layer-2's left D^-1/2). 256B L2-resident gathers,
// int4 neighbor fetch -> 4 independent loads per wait. No LDS.
// ---------------------------------------------------------------------------
__global__ __launch_bounds__(512) void k_agg1(const int* __restrict__ cnt,
                                              const int* __restrict__ nbr,
                                              const float* __restrict__ xp,
                                              float* __restrict__ h1s) {
    const int wave = threadIdx.x >> 6;
    const int lane = threadIdx.x & 63;
    const int i = blockIdx.x * 8 + wave;

    const int c = min(cnt[i], CAP);
    const float di = 1.0f / sqrtf((float)(cnt[i] + 1));
    float a = xp[(size_t)i * HH + lane];  // self (already dinv_i-scaled)
    const int* nb = nbr + (size_t)i * CAP;

    int k = 0;
    for (; k + 4 <= c; k += 4) {
        const int4 j4 = *(const int4*)(nb + k);   // 16B-aligned (CAP*4 stride)
        const float a0 = xp[(size_t)j4.x * HH + lane];
        const float a1 = xp[(size_t)j4.y * HH + lane];
        const float a2 = xp[(size_t)j4.z * HH + lane];
        const float a3 = xp[(size_t)j4.w * HH + lane];
        a += (a0 + a1) + (a2 + a3);
    }
    for (; k < c; ++k) a += xp[(size_t)nb[k] * HH + lane];

    h1s[(size_t)i * HH + lane] = di * fmaxf(di * a, 0.f);
}

// ---------------------------------------------------------------------------
// k_layer2: agg2 = dinv_i*(h1s_i + sum_nbr h1s_j); out = log_softmax(relu(agg2@W2))
// ---------------------------------------------------------------------------
__global__ __launch_bounds__(512) void k_layer2(const float* __restrict__ W2,
                                                const int* __restrict__ cnt,
                                                const int* __restrict__ nbr,
                                                const float* __restrict__ h1s,
                                                float* __restrict__ out) {
    __shared__ float s_W2[HH * CC];   // 4 KB
    __shared__ float s_a[8][HH];      // 2 KB
    for (int t = threadIdx.x; t < HH * CC; t += 512) s_W2[t] = W2[t];
    __syncthreads();

    const int wave = threadIdx.x >> 6;
    const int lane = threadIdx.x & 63;
    const int i = blockIdx.x * 8 + wave;

    const int c = min(cnt[i], CAP);
    float a = h1s[(size_t)i * HH + lane];  // self
    const int* nb = nbr + (size_t)i * CAP;

    int k = 0;
    for (; k + 4 <= c; k += 4) {
        const int4 j4 = *(const int4*)(nb + k);
        const float a0 = h1s[(size_t)j4.x * HH + lane];
        const float a1 = h1s[(size_t)j4.y * HH + lane];
        const float a2 = h1s[(size_t)j4.z * HH + lane];
        const float a3 = h1s[(size_t)j4.w * HH + lane];
        a += (a0 + a1) + (a2 + a3);
    }
    for (; k < c; ++k) a += h1s[(size_t)nb[k] * HH + lane];
    s_a[wave][lane] = a * (1.0f / sqrtf((float)(cnt[i] + 1)));
    __syncthreads();

    float h = 0.f;
    if (lane < CC) {
        #pragma unroll
        for (int o = 0; o < HH; ++o) h += s_a[wave][o] * s_W2[o * CC + lane];
        h = fmaxf(h, 0.f);
    }
    // log_softmax across 16-lane groups (lanes>=16 compute on h=0, never stored)
    float m = h;
    for (int d = 8; d >= 1; d >>= 1) m = fmaxf(m, __shfl_xor(m, d, 16));
    const float e = expf(h - m);
    float s = e;
    for (int d = 8; d >= 1; d >>= 1) s += __shfl_xor(s, d, 16);
    const float r = (h - m) - logf(s);
    if (lane < CC) out[(size_t)i * CC + lane] = r;
}

// ---------------------------------------------------------------------------
// Workspace: cnt[NN] int | nbr[NN*CAP] int | bmp8[NV4] u8 (37.75 MB, 8B-align)
//            | xp[NN*HH] f32 | h1s[NN*HH] f32   — ~50 MB total.
// No memset needed: k_compact writes cnt unconditionally (no atomics).
// ---------------------------------------------------------------------------
extern "C" void kernel_launch(void* const* d_in, const int* in_sizes, int n_in,
                              void* d_out, int out_size, void* d_ws, size_t ws_size,
                              hipStream_t stream) {
    const float* x   = (const float*)d_in[0];
    const float* adj = (const float*)d_in[1];
    const float* W1  = (const float*)d_in[2];
    const float* W2  = (const float*)d_in[3];
    float* out = (float*)d_out;

    char* p = (char*)d_ws;
    int*   cnt  = (int*)p;            p += (size_t)NN * sizeof(int);
    int*   nbr  = (int*)p;            p += (size_t)NN * CAP * sizeof(int);
    unsigned char* bmp8 = (unsigned char*)p;  p += (size_t)NV4;
    float* xp   = (float*)p;          p += (size_t)NN * HH * sizeof(float);
    float* h1s  = (float*)p;

    k_scan<<<NBLD, 256, 0, stream>>>(adj, bmp8);
    k_compact<<<NN / 4, 256, 0, stream>>>((const u64*)bmp8, cnt, nbr);
    k_proj<<<NN / 8, 512, 0, stream>>>(W1, cnt, x, xp);
    k_agg1<<<NN / 8, 512, 0, stream>>>(cnt, nbr, xp, h1s);
    k_layer2<<<NN / 8, 512, 0, stream>>>(W2, cnt, nbr, h1s, out);
}